// Round 10
// baseline (179.857 us; speedup 1.0000x reference)
//
#include <hip/hip_runtime.h>
#include <stdint.h>

typedef unsigned short u16;
typedef unsigned int u32;

#define NTOK 2048
#define CDIM 1024
#define BSZ  4
#define MTOT (BSZ * NTOK)
#define QKVD 3072
#define SM_SCALE 0.02209708691207961f  // 1/sqrt(2048)

typedef __bf16 bf16x8 __attribute__((ext_vector_type(8)));
typedef float f32x4 __attribute__((ext_vector_type(4)));

__device__ __forceinline__ u16 f2bf(float f) {
  u32 u = __float_as_uint(f);
  u += 0x7fffu + ((u >> 16) & 1u);   // round-to-nearest-even
  return (u16)(u >> 16);
}

// ---------------- W fp32 -> bf16 convert (+ RS zero fold-in) ----------------
__global__ __launch_bounds__(256) void wconv_kernel(const float* __restrict__ W,
                                                    u16* __restrict__ Wb, int n8,
                                                    float* __restrict__ RS) {
  int i = blockIdx.x * 256 + threadIdx.x;
  if (i < MTOT) RS[i] = 0.f;
  if (i >= n8) return;
  const float4* p = (const float4*)W + (size_t)i * 2;
  float4 a = p[0], b = p[1];
  uint4 o;
  o.x = (u32)f2bf(a.x) | ((u32)f2bf(a.y) << 16);
  o.y = (u32)f2bf(a.z) | ((u32)f2bf(a.w) << 16);
  o.z = (u32)f2bf(b.x) | ((u32)f2bf(b.y) << 16);
  o.w = (u32)f2bf(b.z) | ((u32)f2bf(b.w) << 16);
  ((uint4*)Wb)[i] = o;
}

// ---------------- one-pass transpose + LayerNorm: x[B,C,N] -> h[B*N, C] bf16 ----
__global__ __launch_bounds__(512) void ln_kernel(const float* __restrict__ x,
                                                 const float* __restrict__ gamma,
                                                 const float* __restrict__ beta,
                                                 u16* __restrict__ h) {
  int blk = blockIdx.x;          // BSZ * (NTOK/32) = 256
  int b = blk >> 6;
  int n0 = (blk & 63) << 5;
  int t = threadIdx.x;
  int nl = t & 31;               // token lane
  int cp = t >> 5;               // 0..15 c-partition
  const float* xb = x + (size_t)b * CDIM * NTOK + n0 + nl;

  float v[64];
  float s = 0.f, ss = 0.f;
#pragma unroll
  for (int k = 0; k < 64; ++k) {
    v[k] = xb[(size_t)(cp + (k << 4)) * NTOK];
    s += v[k]; ss += v[k] * v[k];
  }
  __shared__ float ps[16][32], pss[16][32];
  __shared__ float mean_s[32], rstd_s[32];
  ps[cp][nl] = s; pss[cp][nl] = ss;
  __syncthreads();
  if (t < 32) {
    float m = 0.f, q = 0.f;
#pragma unroll
    for (int p = 0; p < 16; ++p) { m += ps[p][t]; q += pss[p][t]; }
    float mu = m * (1.f / CDIM);
    float var = q * (1.f / CDIM) - mu * mu;
    mean_s[t] = mu;
    rstd_s[t] = rsqrtf(var + 1e-5f);
  }
  __syncthreads();
  float mu_n = mean_s[nl], rs_n = rstd_s[nl];

  __shared__ float tile[64][33];
  int tn = t >> 4, cl = t & 15;
#pragma unroll
  for (int kk = 0; kk < 16; ++kk) {
    __syncthreads();
#pragma unroll
    for (int i = 0; i < 4; ++i) {
      int c = (kk << 6) + (i << 4) + cp;
      tile[(i << 4) + cp][nl] = (v[(kk << 2) + i] - mu_n) * rs_n * gamma[c] + beta[c];
    }
    __syncthreads();
    uint2 pk;
    pk.x = (u32)f2bf(tile[(cl << 2) + 0][tn]) | ((u32)f2bf(tile[(cl << 2) + 1][tn]) << 16);
    pk.y = (u32)f2bf(tile[(cl << 2) + 2][tn]) | ((u32)f2bf(tile[(cl << 2) + 3][tn]) << 16);
    *(uint2*)&h[(size_t)(b * NTOK + n0 + tn) * CDIM + (kk << 6) + (cl << 2)] = pk;
  }
}

__device__ __forceinline__ void gld_lds16(const void* g, void* l) {
  __builtin_amdgcn_global_load_lds(
      (const __attribute__((address_space(1))) void*)g,
      (__attribute__((address_space(3))) void*)l, 16, 0, 0);
}

// ============== 8-phase 256x256 pipelined GEMM (QKV / QK^T) ==============
// K must be 1024 (16 tiles of BK=64, 8 iterations of 2 tiles).
// 512 thr, 8 waves 2Mx4N, per-wave 128x64. LDS 128KB: A(c)=[256][128B] @c*32K,
// B(c) @65536+c*32K. Row-XOR swizzle on bits 4-6; staged via inverse-swizzled
// global source. Stage rotation = region freeing order; vmcnt(4) at phase 4/8
// boundaries (after MFMA, before barrier -> collective).
__device__ __forceinline__ void stage_half8(const char* g, long ld, char* region,
                                            int srow0, int scb, int wave) {
#pragma unroll
  for (int i = 0; i < 2; ++i)
    gld_lds16(g + (long)(srow0 + i * 64) * ld + scb,
              region + wave * 1024 + i * 8192);
}

template <int EPI>
__global__ __launch_bounds__(512, 2) void gemm8_kernel(
    const u16* __restrict__ A, int lda, long sA,
    const u16* __restrict__ B, int ldb, long sB,
    const float* __restrict__ bias,   // EPI0
    const float* __restrict__ pos,    // EPI1
    u16* __restrict__ QD,             // EPI0: dense q | EPI1: S out
    int ldc, long sC,
    u16* __restrict__ KD,             // EPI0: dense k
    u16* __restrict__ VT,             // EPI0: v transposed [b][c][j]
    float* __restrict__ RS)           // EPI1: atomic row sums
{
  __shared__ char smem[131072];

  // chunked bijective XCD swizzle
  const int GX = gridDim.x, GY = gridDim.y;
  const int hb = ((int)blockIdx.z * GY + blockIdx.y) * GX + blockIdx.x;
  const int MX = GX >> 3;
  const int k8 = hb & 7, j8 = hb >> 3;
  const int m = k8 * MX + (j8 % MX);
  const int rest = j8 / MX;
  const int n = rest % GY;
  const int bz = rest / GY;

  A += (size_t)bz * sA;
  B += (size_t)bz * sB;
  const int bm0 = m * 256;
  const int bn0 = n * 256;

  const int t = threadIdx.x;
  const int wave = t >> 6;
  const int wm = wave >> 2;      // 0..1 : rows wm*128
  const int wn = wave & 3;       // 0..3 : cols wn*64
  const int lr = t & 15, lk = (t & 63) >> 4;

  // frag LDS offsets (within an A/B 32KB region)
  const int xo0 = (lk * 16) ^ ((lr & 7) << 4);
  const int xo1 = (64 + lk * 16) ^ ((lr & 7) << 4);
  const int aoff = (wm * 128 + lr) * 128;
  const int boff = (wn * 64 + lr) * 128;

  // stage source decomposition (inverse swizzle on global col bytes)
  const int srow0 = t >> 3;                              // 0..63
  const int scb = (((t & 7) ^ ((t >> 3) & 7)) << 4);     // swizzled col byte

  const long lda2 = (long)lda * 2, ldb2 = (long)ldb * 2;
  const char* Agb = (const char*)A + (size_t)bm0 * lda2;
  const char* Bgb = (const char*)B + (size_t)bn0 * ldb2;

#define ST_A(kt, h, buf) stage_half8(Agb + (long)(h) * 128 * lda2 + (long)(kt) * 128, \
                                     lda2, smem + (buf) * 32768 + (h) * 16384, srow0, scb, wave)
#define ST_B(kt, h, buf) stage_half8(Bgb + (long)(h) * 128 * ldb2 + (long)(kt) * 128, \
                                     ldb2, smem + 65536 + (buf) * 32768 + (h) * 16384, srow0, scb, wave)

  f32x4 acc[8][4];
#pragma unroll
  for (int mf = 0; mf < 8; ++mf)
#pragma unroll
    for (int nf = 0; nf < 4; ++nf) acc[mf][nf] = (f32x4){0.f, 0.f, 0.f, 0.f};

  // prologue: tile0 (buf0) fully + B of tile1 (buf1)
  ST_B(0, 0, 0); ST_B(0, 1, 0); ST_A(0, 0, 0); ST_A(0, 1, 0);
  ST_B(1, 0, 1); ST_B(1, 1, 1);
  asm volatile("s_waitcnt vmcnt(4)" ::: "memory");
  __builtin_amdgcn_sched_barrier(0);
  __builtin_amdgcn_s_barrier();

  bf16x8 bv[4][2], av[2][2];

#define PH(c, q, RB, STG, VM)                                                    \
  {                                                                              \
    if (RB) {                                                                    \
      _Pragma("unroll") for (int nf = 0; nf < 4; ++nf) {                         \
        bv[nf][0] = *(const bf16x8*)(smem + 65536 + (c) * 32768 + boff + nf * 2048 + xo0); \
        bv[nf][1] = *(const bf16x8*)(smem + 65536 + (c) * 32768 + boff + nf * 2048 + xo1); \
      }                                                                          \
    }                                                                            \
    av[0][0] = *(const bf16x8*)(smem + (c) * 32768 + aoff + (2 * (q)) * 2048 + xo0);     \
    av[0][1] = *(const bf16x8*)(smem + (c) * 32768 + aoff + (2 * (q)) * 2048 + xo1);     \
    av[1][0] = *(const bf16x8*)(smem + (c) * 32768 + aoff + (2 * (q) + 1) * 2048 + xo0); \
    av[1][1] = *(const bf16x8*)(smem + (c) * 32768 + aoff + (2 * (q) + 1) * 2048 + xo1); \
    STG;                                                                         \
    __builtin_amdgcn_sched_barrier(0);                                           \
    __builtin_amdgcn_s_barrier();                                                \
    asm volatile("s_waitcnt lgkmcnt(0)" ::: "memory");                           \
    __builtin_amdgcn_sched_barrier(0);                                           \
    __builtin_amdgcn_s_setprio(1);                                               \
    _Pragma("unroll") for (int i = 0; i < 2; ++i)                                \
      _Pragma("unroll") for (int nf = 0; nf < 4; ++nf) {                         \
        acc[2 * (q) + i][nf] = __builtin_amdgcn_mfma_f32_16x16x32_bf16(          \
            av[i][0], bv[nf][0], acc[2 * (q) + i][nf], 0, 0, 0);                 \
        acc[2 * (q) + i][nf] = __builtin_amdgcn_mfma_f32_16x16x32_bf16(          \
            av[i][1], bv[nf][1], acc[2 * (q) + i][nf], 0, 0, 0);                 \
      }                                                                          \
    __builtin_amdgcn_s_setprio(0);                                               \
    VM;                                                                          \
    __builtin_amdgcn_sched_barrier(0);                                           \
    __builtin_amdgcn_s_barrier();                                                \
  }

#pragma unroll 1
  for (int u = 0; u < 8; ++u) {
    const bool g = (u < 7);
    // tile 2u in buf0
    PH(0, 0, 1, { ST_A(2 * u + 1, 0, 1); }, {});
    PH(0, 1, 0, { ST_A(2 * u + 1, 1, 1); }, {});
    PH(0, 2, 0, { if (g) ST_B(2 * u + 2, 0, 0); }, {});
    PH(0, 3, 0, { if (g) ST_B(2 * u + 2, 1, 0); },
       { if (g) { asm volatile("s_waitcnt vmcnt(4)" ::: "memory"); }
         else   { asm volatile("s_waitcnt vmcnt(0)" ::: "memory"); } });
    // tile 2u+1 in buf1
    PH(1, 0, 1, { if (g) ST_A(2 * u + 2, 0, 0); }, {});
    PH(1, 1, 0, { if (g) ST_A(2 * u + 2, 1, 0); }, {});
    PH(1, 2, 0, { if (g) ST_B(2 * u + 3, 0, 1); }, {});
    PH(1, 3, 0, { if (g) ST_B(2 * u + 3, 1, 1); },
       { if (g) { asm volatile("s_waitcnt vmcnt(4)" ::: "memory"); } });
  }
#undef PH
#undef ST_A
#undef ST_B

  // epilogue: lane holds col fixed, rows lk*4 + r consecutive
#pragma unroll
  for (int mf = 0; mf < 8; ++mf) {
    const int row = bm0 + wm * 128 + mf * 16 + (lk << 2);
    float rs[4] = {0.f, 0.f, 0.f, 0.f};
#pragma unroll
    for (int nf = 0; nf < 4; ++nf) {
      const int col = bn0 + wn * 64 + nf * 16 + lr;
      f32x4 v = acc[mf][nf];
      if (EPI == 0) {
        const float bb = bias[col];
        if (col < CDIM) {
#pragma unroll
          for (int r = 0; r < 4; ++r)
            QD[(size_t)(row + r) * CDIM + col] = f2bf(v[r] + bb);
        } else if (col < 2 * CDIM) {
          const int c1 = col - CDIM;
#pragma unroll
          for (int r = 0; r < 4; ++r)
            KD[(size_t)(row + r) * CDIM + c1] = f2bf(v[r] + bb);
        } else {
          const int bq = row >> 11;
          const int j = row & (NTOK - 1);
          const int c2 = col - 2 * CDIM;
          uint2 pk;
          pk.x = (u32)f2bf(v[0] + bb) | ((u32)f2bf(v[1] + bb) << 16);
          pk.y = (u32)f2bf(v[2] + bb) | ((u32)f2bf(v[3] + bb) << 16);
          *(uint2*)&VT[((size_t)bq * CDIM + c2) * NTOK + j] = pk;
        }
      } else {
        u16* Cp = QD + (size_t)bz * sC;
#pragma unroll
        for (int r = 0; r < 4; ++r) {
          float sv = v[r] * SM_SCALE + pos[(size_t)(row + r) * NTOK + col];
          float e = __expf(sv);
          rs[r] += e;
          Cp[(size_t)(row + r) * ldc + col] = f2bf(e);
        }
      }
    }
    if (EPI == 1) {
#pragma unroll
      for (int r = 0; r < 4; ++r) {
#pragma unroll
        for (int mk = 1; mk <= 8; mk <<= 1)
          rs[r] += __shfl_xor(rs[r], mk, 64);
      }
      if (lr == 0) {
        float* rp = RS + (size_t)bz * NTOK + row;
        atomicAdd(rp + 0, rs[0]);
        atomicAdd(rp + 1, rs[1]);
        atomicAdd(rp + 2, rs[2]);
        atomicAdd(rp + 3, rs[3]);
      }
    }
  }
}

// ============== m97-style 128x128 GEMM (PV only, proven) ==============
__device__ __forceinline__ void stage128(const char* g, long ld, char* lds, int t) {
  const long rb = (long)(t >> 2) * ld + ((((t & 3) - (t >> 3)) & 3) << 4);
#pragma unroll
  for (int i = 0; i < 2; ++i)
    gld_lds16(g + rb + (long)(i * 64) * ld,
              lds + ((t >> 6) << 10) + (i << 12));
}

__global__ __launch_bounds__(256, 3) void gemm_pv_kernel(
    const u16* __restrict__ A, int lda, long sA,
    const u16* __restrict__ B, int ldb, long sB, int K,
    float* __restrict__ CT, long sCT,
    const float* __restrict__ RS)
{
  __shared__ char smem[32768];

  const int GX = gridDim.x, GY = gridDim.y;
  const int hb = ((int)blockIdx.z * GY + blockIdx.y) * GX + blockIdx.x;
  const int MX = GX >> 3;
  const int k8 = hb & 7, j8 = hb >> 3;
  const int m = k8 * MX + (j8 % MX);
  const int rest = j8 / MX;
  const int n = rest % GY;
  const int bz = rest / GY;

  A += (size_t)bz * sA;
  B += (size_t)bz * sB;
  const int bm0 = m * 128;
  const int bn0 = n * 128;

  const int t = threadIdx.x;
  const int wave = t >> 6;
  const int wm = wave >> 1, wn = wave & 1;
  const int MROW = wm * 64, NCOL = wn * 64;
  const int lr = t & 15, lk = (t & 63) >> 4;
  const int fragoff = lr * 64 + (((lk + (lr >> 1)) & 3) << 4);

  const long lda2 = (long)lda * 2, ldb2 = (long)ldb * 2;
  const char* Agb = (const char*)A + (size_t)bm0 * lda2;
  const char* Bgb = (const char*)B + (size_t)bn0 * ldb2;

  f32x4 acc[4][4];
#pragma unroll
  for (int mm = 0; mm < 4; ++mm)
#pragma unroll
    for (int nn = 0; nn < 4; ++nn) acc[mm][nn] = (f32x4){0.f, 0.f, 0.f, 0.f};

  const int nt = K >> 6;
  for (int kt = 0; kt < nt; ++kt) {
    __syncthreads();
    const long kb = (long)kt * 128;
    stage128(Agb + kb,      lda2, smem,          t);
    stage128(Agb + kb + 64, lda2, smem + 8192,   t);
    stage128(Bgb + kb,      ldb2, smem + 16384,  t);
    stage128(Bgb + kb + 64, ldb2, smem + 24576,  t);
    __syncthreads();

#pragma unroll
    for (int ks = 0; ks < 2; ++ks) {
      const char* Ab = smem + ks * 8192;
      const char* Bb = smem + 16384 + ks * 8192;
      bf16x8 av[4], bv[4];
#pragma unroll
      for (int i = 0; i < 4; ++i)
        av[i] = *(const bf16x8*)(Ab + (MROW + i * 16) * 64 + fragoff);
#pragma unroll
      for (int i = 0; i < 4; ++i)
        bv[i] = *(const bf16x8*)(Bb + (NCOL + i * 16) * 64 + fragoff);
#pragma unroll
      for (int mm = 0; mm < 4; ++mm)
#pragma unroll
        for (int nn = 0; nn < 4; ++nn)
          acc[mm][nn] = __builtin_amdgcn_mfma_f32_16x16x32_bf16(av[mm], bv[nn],
                                                                acc[mm][nn], 0, 0, 0);
    }
  }

#pragma unroll
  for (int mm = 0; mm < 4; ++mm) {
    const int row = bm0 + MROW + mm * 16 + (lk << 2);
    const float4 rsv = *(const float4*)(RS + (size_t)bz * NTOK + row);
    float inv[4] = {1.f / rsv.x, 1.f / rsv.y, 1.f / rsv.z, 1.f / rsv.w};
#pragma unroll
    for (int nn = 0; nn < 4; ++nn) {
      const int col = bn0 + NCOL + nn * 16 + lr;
      f32x4 v = acc[mm][nn];
      float* o = CT + (size_t)bz * sCT + (size_t)col * NTOK + row;
      f32x4 w;
      w[0] = v[0] * inv[0]; w[1] = v[1] * inv[1];
      w[2] = v[2] * inv[2]; w[3] = v[3] * inv[3];
      *(f32x4*)o = w;
    }
  }
}

extern "C" void kernel_launch(void* const* d_in, const int* in_sizes, int n_in,
                              void* d_out, int out_size, void* d_ws, size_t ws_size,
                              hipStream_t stream) {
  const float* x     = (const float*)d_in[0];
  const float* pos   = (const float*)d_in[1];
  const float* gamma = (const float*)d_in[2];
  const float* beta  = (const float*)d_in[3];
  const float* W     = (const float*)d_in[4];
  const float* bias  = (const float*)d_in[5];
  float* out = (float*)d_out;
  char* ws = (char*)d_ws;

  u16* Wb  = (u16*)(ws);                    //  6 MB  [3072,1024] bf16
  u16* h   = (u16*)(ws + (6ll << 20));      // 16 MB  [8192,1024] bf16
  u16* qd  = (u16*)(ws + (22ll << 20));     // 16 MB  dense q
  u16* kd  = (u16*)(ws + (38ll << 20));     // 16 MB  dense k
  u16* vT  = (u16*)(ws + (54ll << 20));     // 16 MB  [4][1024][2048] bf16
  u16* S   = (u16*)(ws + (70ll << 20));     // 32 MB  [4][2048][2048] bf16 (P~)
  float* RS = (float*)(ws + (102ll << 20)); // 32 KB row sums

  wconv_kernel<<<dim3((QKVD * CDIM / 8 + 255) / 256), 256, 0, stream>>>(
      W, Wb, QKVD * CDIM / 8, RS);
  ln_kernel<<<dim3(BSZ * (NTOK / 32)), 512, 0, stream>>>(x, gamma, beta, h);

  // qkv = h @ W^T + b  (M=8192, N=3072, K=1024); q,k dense; v transposed
  gemm8_kernel<0><<<dim3(MTOT / 256, QKVD / 256, 1), 512, 0, stream>>>(
      h, CDIM, 0, Wb, CDIM, 0,
      bias, nullptr, qd, 0, 0, kd, vT, nullptr);

  // P~ = exp(q @ k^T * scale + pos), rowsums -> RS (per batch 2048x2048, K=1024)
  gemm8_kernel<1><<<dim3(NTOK / 256, NTOK / 256, BSZ), 512, 0, stream>>>(
      qd, CDIM, (long)NTOK * CDIM, kd, CDIM, (long)NTOK * CDIM,
      nullptr, pos, S, NTOK, (long)NTOK * NTOK, nullptr, nullptr, RS);

  // out = (P~ @ vT^T) / rowsum, transposed f32 write
  gemm_pv_kernel<<<dim3(NTOK / 128, CDIM / 128, BSZ), 256, 0, stream>>>(
      S, NTOK, (long)NTOK * NTOK, vT, NTOK, (long)CDIM * NTOK, NTOK,
      out, (long)CDIM * NTOK, RS);
}

// Round 11
// 177.626 us; speedup vs baseline: 1.0126x; 1.0126x over previous
//
#include <hip/hip_runtime.h>
#include <stdint.h>

typedef unsigned short u16;
typedef unsigned int u32;

#define NTOK 2048
#define CDIM 1024
#define BSZ  4
#define MTOT (BSZ * NTOK)
#define QKVD 3072
#define SM_SCALE 0.02209708691207961f   // 1/sqrt(2048)
#define INV_SM_SCALE 45.254833995939045f

typedef __bf16 bf16x8 __attribute__((ext_vector_type(8)));
typedef float f32x4 __attribute__((ext_vector_type(4)));

__device__ __forceinline__ u16 f2bf(float f) {
  u32 u = __float_as_uint(f);
  u += 0x7fffu + ((u >> 16) & 1u);   // round-to-nearest-even
  return (u16)(u >> 16);
}

// ---------------- W fp32 -> bf16 convert (+ RS zero fold-in) ----------------
__global__ __launch_bounds__(256) void wconv_kernel(const float* __restrict__ W,
                                                    u16* __restrict__ Wb, int n8,
                                                    float* __restrict__ RS) {
  int i = blockIdx.x * 256 + threadIdx.x;
  if (i < MTOT) RS[i] = 0.f;
  if (i >= n8) return;
  const float4* p = (const float4*)W + (size_t)i * 2;
  float4 a = p[0], b = p[1];
  uint4 o;
  o.x = (u32)f2bf(a.x) | ((u32)f2bf(a.y) << 16);
  o.y = (u32)f2bf(a.z) | ((u32)f2bf(a.w) << 16);
  o.z = (u32)f2bf(b.x) | ((u32)f2bf(b.y) << 16);
  o.w = (u32)f2bf(b.z) | ((u32)f2bf(b.w) << 16);
  ((uint4*)Wb)[i] = o;
}

// ---------------- one-pass transpose + LayerNorm: x[B,C,N] -> h[B*N, C] bf16 ----
__global__ __launch_bounds__(512) void ln_kernel(const float* __restrict__ x,
                                                 const float* __restrict__ gamma,
                                                 const float* __restrict__ beta,
                                                 u16* __restrict__ h) {
  int blk = blockIdx.x;          // BSZ * (NTOK/32) = 256
  int b = blk >> 6;
  int n0 = (blk & 63) << 5;
  int t = threadIdx.x;
  int nl = t & 31;               // token lane
  int cp = t >> 5;               // 0..15 c-partition
  const float* xb = x + (size_t)b * CDIM * NTOK + n0 + nl;

  float v[64];
  float s = 0.f, ss = 0.f;
#pragma unroll
  for (int k = 0; k < 64; ++k) {
    v[k] = xb[(size_t)(cp + (k << 4)) * NTOK];
    s += v[k]; ss += v[k] * v[k];
  }
  __shared__ float ps[16][32], pss[16][32];
  __shared__ float mean_s[32], rstd_s[32];
  ps[cp][nl] = s; pss[cp][nl] = ss;
  __syncthreads();
  if (t < 32) {
    float m = 0.f, q = 0.f;
#pragma unroll
    for (int p = 0; p < 16; ++p) { m += ps[p][t]; q += pss[p][t]; }
    float mu = m * (1.f / CDIM);
    float var = q * (1.f / CDIM) - mu * mu;
    mean_s[t] = mu;
    rstd_s[t] = rsqrtf(var + 1e-5f);
  }
  __syncthreads();
  float mu_n = mean_s[nl], rs_n = rstd_s[nl];

  __shared__ float tile[64][33];
  int tn = t >> 4, cl = t & 15;
#pragma unroll
  for (int kk = 0; kk < 16; ++kk) {
    __syncthreads();
#pragma unroll
    for (int i = 0; i < 4; ++i) {
      int c = (kk << 6) + (i << 4) + cp;     // = kk*64 + i*16 + cp
      tile[(i << 4) + cp][nl] = (v[(kk << 2) + i] - mu_n) * rs_n * gamma[c] + beta[c];
    }
    __syncthreads();
    uint2 pk;
    pk.x = (u32)f2bf(tile[(cl << 2) + 0][tn]) | ((u32)f2bf(tile[(cl << 2) + 1][tn]) << 16);
    pk.y = (u32)f2bf(tile[(cl << 2) + 2][tn]) | ((u32)f2bf(tile[(cl << 2) + 3][tn]) << 16);
    *(uint2*)&h[(size_t)(b * NTOK + n0 + tn) * CDIM + (kk << 6) + (cl << 2)] = pk;
  }
}

// ---------------- m97-style bf16 GEMM, B^T layout, 128x128 tile ----------------
// C[row,col] = sum_k A[row,k]*B[col,k]. BK=64, 4 waves (2Mx2N), 32KB LDS,
// single-buffered stage->sync->compute; cross-block overlap does the pipelining.
// EPI0 routes q/k dense + v transposed; EPI1 preloads pos into the accumulator
// (hidden under prologue staging) and fuses unnormalized softmax (exp + row-sum
// atomics); EPI2 divides by sums, writes transposed f32.
__device__ __forceinline__ void gld_lds16(const void* g, void* l) {
  __builtin_amdgcn_global_load_lds(
      (const __attribute__((address_space(1))) void*)g,
      (__attribute__((address_space(3))) void*)l, 16, 0, 0);
}

// stage a [128 rows][64B] k-half region with 256 threads (2 gld/thread).
// LDS dest linear (wave-uniform + lane*16); global source slot-permuted so
// LDS (row, s) holds global slot (s - (row>>1))&3  -> conflict-free reads.
__device__ __forceinline__ void stage128(const char* g, long ld, char* lds, int t) {
  const long rb = (long)(t >> 2) * ld + ((((t & 3) - (t >> 3)) & 3) << 4);
#pragma unroll
  for (int i = 0; i < 2; ++i)
    gld_lds16(g + rb + (long)(i * 64) * ld,
              lds + ((t >> 6) << 10) + (i << 12));
}

template <int EPI>
__global__ __launch_bounds__(256, 3) void gemm_kernel(
    const u16* __restrict__ A, int lda, long sA,
    const u16* __restrict__ B, int ldb, long sB, int K,
    const float* __restrict__ bias,   // EPI0
    const float* __restrict__ pos,    // EPI1
    u16* __restrict__ Cb, int ldc, long sC,  // EPI0: qd | EPI1: S bf16 out
    u16* __restrict__ KD,             // EPI0: dense k out [row][c]
    u16* __restrict__ VT,             // EPI0: transposed v out [b][c][j]
    float* __restrict__ CT, long sCT, // EPI2: f32 out [col*NTOK + row]
    float* __restrict__ RS)           // EPI1: atomic row sums; EPI2: read
{
  // LDS: A kh0 @0, A kh1 @8K, B kh0 @16K, B kh1 @24K  (32KB total)
  __shared__ char smem[32768];

  // chunked bijective XCD swizzle: xcd k owns m-chunk, intra m-fastest.
  const int GX = gridDim.x, GY = gridDim.y;
  const int hb = ((int)blockIdx.z * GY + blockIdx.y) * GX + blockIdx.x;
  const int MX = GX >> 3;
  const int k8 = hb & 7, j8 = hb >> 3;
  const int m = k8 * MX + (j8 % MX);
  const int rest = j8 / MX;
  const int n = rest % GY;
  const int bz = rest / GY;

  A += (size_t)bz * sA;
  B += (size_t)bz * sB;
  const int bm0 = m * 128;
  const int bn0 = n * 128;

  const int t = threadIdx.x;
  const int wave = t >> 6;
  const int wm = wave >> 1, wn = wave & 1;
  const int MROW = wm * 64, NCOL = wn * 64;
  const int lr = t & 15, lk = (t & 63) >> 4;
  // per-lane fragment byte offset within a k-half region (bank-perfect)
  const int fragoff = lr * 64 + (((lk + (lr >> 1)) & 3) << 4);

  const long lda2 = (long)lda * 2, ldb2 = (long)ldb * 2;
  const char* Agb = (const char*)A + (size_t)bm0 * lda2;
  const char* Bgb = (const char*)B + (size_t)bn0 * ldb2;

  f32x4 acc[4][4];
  if (EPI == 1) {
    // preload position bias into the accumulator (C-operand carries it through
    // the K-loop); loads overlap the prologue global->LDS staging latency.
#pragma unroll
    for (int mm = 0; mm < 4; ++mm) {
      const int row = bm0 + MROW + mm * 16 + (lk << 2);
#pragma unroll
      for (int nn = 0; nn < 4; ++nn) {
        const int col = bn0 + NCOL + nn * 16 + lr;
#pragma unroll
        for (int r = 0; r < 4; ++r)
          acc[mm][nn][r] = pos[(size_t)(row + r) * NTOK + col] * INV_SM_SCALE;
      }
    }
  } else {
#pragma unroll
    for (int mm = 0; mm < 4; ++mm)
#pragma unroll
      for (int nn = 0; nn < 4; ++nn) acc[mm][nn] = (f32x4){0.f, 0.f, 0.f, 0.f};
  }

  const int nt = K >> 6;
  for (int kt = 0; kt < nt; ++kt) {
    __syncthreads();   // all prior LDS reads complete everywhere
    const long kb = (long)kt * 128;
    stage128(Agb + kb,      lda2, smem,          t);
    stage128(Agb + kb + 64, lda2, smem + 8192,   t);
    stage128(Bgb + kb,      ldb2, smem + 16384,  t);
    stage128(Bgb + kb + 64, ldb2, smem + 24576,  t);
    __syncthreads();   // implies vmcnt(0): staged data landed

#pragma unroll
    for (int ks = 0; ks < 2; ++ks) {
      const char* Ab = smem + ks * 8192;
      const char* Bb = smem + 16384 + ks * 8192;
      bf16x8 av[4], bv[4];
#pragma unroll
      for (int i = 0; i < 4; ++i)
        av[i] = *(const bf16x8*)(Ab + (MROW + i * 16) * 64 + fragoff);
#pragma unroll
      for (int i = 0; i < 4; ++i)
        bv[i] = *(const bf16x8*)(Bb + (NCOL + i * 16) * 64 + fragoff);
#pragma unroll
      for (int mm = 0; mm < 4; ++mm)
#pragma unroll
        for (int nn = 0; nn < 4; ++nn)
          acc[mm][nn] = __builtin_amdgcn_mfma_f32_16x16x32_bf16(av[mm], bv[nn],
                                                                acc[mm][nn], 0, 0, 0);
    }
  }

  // epilogue: lane holds col fixed, rows lk*4 + r consecutive
#pragma unroll
  for (int mm = 0; mm < 4; ++mm) {
    const int row = bm0 + MROW + mm * 16 + (lk << 2);
    float rs[4] = {0.f, 0.f, 0.f, 0.f};   // EPI1 row-sum partials
    float inv[4];
    if (EPI == 2) {
      const float4 rsv = *(const float4*)(RS + (size_t)bz * NTOK + row);
      inv[0] = 1.f / rsv.x; inv[1] = 1.f / rsv.y;
      inv[2] = 1.f / rsv.z; inv[3] = 1.f / rsv.w;
    }
#pragma unroll
    for (int nn = 0; nn < 4; ++nn) {
      const int col = bn0 + NCOL + nn * 16 + lr;
      f32x4 v = acc[mm][nn];
      if (EPI == 0) {
        const float bb = bias[col];
        if (col < CDIM) {
          // dense q
#pragma unroll
          for (int r = 0; r < 4; ++r)
            Cb[(size_t)(row + r) * CDIM + col] = f2bf(v[r] + bb);
        } else if (col < 2 * CDIM) {
          // dense k
          const int c1 = col - CDIM;
#pragma unroll
          for (int r = 0; r < 4; ++r)
            KD[(size_t)(row + r) * CDIM + c1] = f2bf(v[r] + bb);
        } else {
          const int bq = row >> 11;
          const int j = row & (NTOK - 1);
          const int c2 = col - 2 * CDIM;
          uint2 pk;
          pk.x = (u32)f2bf(v[0] + bb) | ((u32)f2bf(v[1] + bb) << 16);
          pk.y = (u32)f2bf(v[2] + bb) | ((u32)f2bf(v[3] + bb) << 16);
          *(uint2*)&VT[((size_t)bq * CDIM + c2) * NTOK + j] = pk;
        }
      } else if (EPI == 1) {
        // P~ = exp((qk + pos/scale)*scale), unnormalized (scores bounded)
        u16* Cp = Cb + (size_t)bz * sC;
#pragma unroll
        for (int r = 0; r < 4; ++r) {
          float e = __expf(v[r] * SM_SCALE);
          rs[r] += e;
          Cp[(size_t)(row + r) * ldc + col] = f2bf(e);
        }
      } else {
        float* o = CT + (size_t)bz * sCT + (size_t)col * NTOK + row;
        f32x4 w;
        w[0] = v[0] * inv[0]; w[1] = v[1] * inv[1];
        w[2] = v[2] * inv[2]; w[3] = v[3] * inv[3];
        *(f32x4*)o = w;
      }
    }
    if (EPI == 1) {
      // reduce rs over the 16 lr-lanes, then one atomic per row
#pragma unroll
      for (int r = 0; r < 4; ++r) {
#pragma unroll
        for (int mk = 1; mk <= 8; mk <<= 1)
          rs[r] += __shfl_xor(rs[r], mk, 64);
      }
      if (lr == 0) {
        float* rp = RS + (size_t)bz * NTOK + row;
        atomicAdd(rp + 0, rs[0]);
        atomicAdd(rp + 1, rs[1]);
        atomicAdd(rp + 2, rs[2]);
        atomicAdd(rp + 3, rs[3]);
      }
    }
  }
}

extern "C" void kernel_launch(void* const* d_in, const int* in_sizes, int n_in,
                              void* d_out, int out_size, void* d_ws, size_t ws_size,
                              hipStream_t stream) {
  const float* x     = (const float*)d_in[0];
  const float* pos   = (const float*)d_in[1];
  const float* gamma = (const float*)d_in[2];
  const float* beta  = (const float*)d_in[3];
  const float* W     = (const float*)d_in[4];
  const float* bias  = (const float*)d_in[5];
  float* out = (float*)d_out;
  char* ws = (char*)d_ws;

  // workspace layout (102 MB + 32 KB)
  u16* Wb  = (u16*)(ws);                    //  6 MB  [3072,1024] bf16
  u16* h   = (u16*)(ws + (6ll << 20));      // 16 MB  [8192,1024] bf16
  u16* qd  = (u16*)(ws + (22ll << 20));     // 16 MB  [8192,1024] bf16 dense q
  u16* kd  = (u16*)(ws + (38ll << 20));     // 16 MB  [8192,1024] bf16 dense k
  u16* vT  = (u16*)(ws + (54ll << 20));     // 16 MB  [4][1024][2048] bf16
  u16* S   = (u16*)(ws + (70ll << 20));     // 32 MB  [4][2048][2048] bf16 (P~)
  float* RS = (float*)(ws + (102ll << 20)); // 32 KB row sums

  wconv_kernel<<<dim3((QKVD * CDIM / 8 + 255) / 256), 256, 0, stream>>>(
      W, Wb, QKVD * CDIM / 8, RS);
  ln_kernel<<<dim3(BSZ * (NTOK / 32)), 512, 0, stream>>>(x, gamma, beta, h);

  // qkv = h @ W^T + b  (M=8192, N=3072, K=1024); q,k dense; v transposed
  gemm_kernel<0><<<dim3(MTOT / 128, QKVD / 128, 1), 256, 0, stream>>>(
      h, CDIM, 0, Wb, CDIM, 0, CDIM,
      bias, nullptr, qd, CDIM, 0, kd, vT, nullptr, 0, nullptr);

  // P~ = exp(q @ k^T * scale + position), row sums -> RS (per batch M=N=2048, K=1024)
  gemm_kernel<1><<<dim3(NTOK / 128, NTOK / 128, BSZ), 256, 0, stream>>>(
      qd, CDIM, (long)NTOK * CDIM, kd, CDIM, (long)NTOK * CDIM, CDIM,
      nullptr, pos, S, NTOK, (long)NTOK * NTOK, nullptr, nullptr, nullptr, 0, RS);

  // out = (P~ @ vT^T) / rowsum, written transposed to [B, C, N] f32
  gemm_kernel<2><<<dim3(NTOK / 128, CDIM / 128, BSZ), 256, 0, stream>>>(
      S, NTOK, (long)NTOK * NTOK, vT, NTOK, (long)CDIM * NTOK, NTOK,
      nullptr, nullptr, nullptr, 0, 0, nullptr, nullptr, out, (long)CDIM * NTOK, RS);
}

// Round 12
// 171.989 us; speedup vs baseline: 1.0457x; 1.0328x over previous
//
#include <hip/hip_runtime.h>
#include <stdint.h>

typedef unsigned short u16;
typedef unsigned int u32;

#define NTOK 2048
#define CDIM 1024
#define BSZ  4
#define MTOT (BSZ * NTOK)
#define QKVD 3072
#define SM_SCALE 0.02209708691207961f   // 1/sqrt(2048)

typedef __bf16 bf16x8 __attribute__((ext_vector_type(8)));
typedef float f32x4 __attribute__((ext_vector_type(4)));

__device__ __forceinline__ u16 f2bf(float f) {
  u32 u = __float_as_uint(f);
  u += 0x7fffu + ((u >> 16) & 1u);   // round-to-nearest-even
  return (u16)(u >> 16);
}

// ---------------- W fp32 -> bf16 convert (+ RS zero fold-in) ----------------
__global__ __launch_bounds__(256) void wconv_kernel(const float* __restrict__ W,
                                                    u16* __restrict__ Wb, int n8,
                                                    float* __restrict__ RS) {
  int i = blockIdx.x * 256 + threadIdx.x;
  if (i < MTOT) RS[i] = 0.f;
  if (i >= n8) return;
  const float4* p = (const float4*)W + (size_t)i * 2;
  float4 a = p[0], b = p[1];
  uint4 o;
  o.x = (u32)f2bf(a.x) | ((u32)f2bf(a.y) << 16);
  o.y = (u32)f2bf(a.z) | ((u32)f2bf(a.w) << 16);
  o.z = (u32)f2bf(b.x) | ((u32)f2bf(b.y) << 16);
  o.w = (u32)f2bf(b.z) | ((u32)f2bf(b.w) << 16);
  ((uint4*)Wb)[i] = o;
}

// ---------------- one-pass transpose + LayerNorm: x[B,C,N] -> h[B*N, C] bf16 ----
__global__ __launch_bounds__(512) void ln_kernel(const float* __restrict__ x,
                                                 const float* __restrict__ gamma,
                                                 const float* __restrict__ beta,
                                                 u16* __restrict__ h) {
  int blk = blockIdx.x;          // BSZ * (NTOK/32) = 256
  int b = blk >> 6;
  int n0 = (blk & 63) << 5;
  int t = threadIdx.x;
  int nl = t & 31;               // token lane
  int cp = t >> 5;               // 0..15 c-partition
  const float* xb = x + (size_t)b * CDIM * NTOK + n0 + nl;

  float v[64];
  float s = 0.f, ss = 0.f;
#pragma unroll
  for (int k = 0; k < 64; ++k) {
    v[k] = xb[(size_t)(cp + (k << 4)) * NTOK];
    s += v[k]; ss += v[k] * v[k];
  }
  __shared__ float ps[16][32], pss[16][32];
  __shared__ float mean_s[32], rstd_s[32];
  ps[cp][nl] = s; pss[cp][nl] = ss;
  __syncthreads();
  if (t < 32) {
    float m = 0.f, q = 0.f;
#pragma unroll
    for (int p = 0; p < 16; ++p) { m += ps[p][t]; q += pss[p][t]; }
    float mu = m * (1.f / CDIM);
    float var = q * (1.f / CDIM) - mu * mu;
    mean_s[t] = mu;
    rstd_s[t] = rsqrtf(var + 1e-5f);
  }
  __syncthreads();
  float mu_n = mean_s[nl], rs_n = rstd_s[nl];

  __shared__ float tile[64][33];
  int tn = t >> 4, cl = t & 15;
#pragma unroll
  for (int kk = 0; kk < 16; ++kk) {
    __syncthreads();
#pragma unroll
    for (int i = 0; i < 4; ++i) {
      int c = (kk << 6) + (i << 4) + cp;     // = kk*64 + i*16 + cp
      tile[(i << 4) + cp][nl] = (v[(kk << 2) + i] - mu_n) * rs_n * gamma[c] + beta[c];
    }
    __syncthreads();
    uint2 pk;
    pk.x = (u32)f2bf(tile[(cl << 2) + 0][tn]) | ((u32)f2bf(tile[(cl << 2) + 1][tn]) << 16);
    pk.y = (u32)f2bf(tile[(cl << 2) + 2][tn]) | ((u32)f2bf(tile[(cl << 2) + 3][tn]) << 16);
    *(uint2*)&h[(size_t)(b * NTOK + n0 + tn) * CDIM + (kk << 6) + (cl << 2)] = pk;
  }
}

// ---------------- m97-style bf16 GEMM, B^T layout, 128x128 tile ----------------
// C[row,col] = sum_k A[row,k]*B[col,k]. BK=64, 4 waves (2Mx2N), 32KB LDS,
// single-buffered stage->sync->compute; cross-block overlap does the pipelining.
// Residency is the performance lever: in-loop unified regs ~120 (<=128), so
// EPI1 requests 4 waves/EU (grid 1024 = exactly 4 blocks/CU, no straggler gen).
__device__ __forceinline__ void gld_lds16(const void* g, void* l) {
  __builtin_amdgcn_global_load_lds(
      (const __attribute__((address_space(1))) void*)g,
      (__attribute__((address_space(3))) void*)l, 16, 0, 0);
}

// stage a [128 rows][64B] k-half region with 256 threads (2 gld/thread).
// LDS dest linear (wave-uniform + lane*16); global source slot-permuted so
// LDS (row, s) holds global slot (s - (row>>1))&3  -> conflict-free reads.
__device__ __forceinline__ void stage128(const char* g, long ld, char* lds, int t) {
  const long rb = (long)(t >> 2) * ld + ((((t & 3) - (t >> 3)) & 3) << 4);
#pragma unroll
  for (int i = 0; i < 2; ++i)
    gld_lds16(g + rb + (long)(i * 64) * ld,
              lds + ((t >> 6) << 10) + (i << 12));
}

template <int EPI>
__global__ __launch_bounds__(256, (EPI == 1) ? 4 : 3) void gemm_kernel(
    const u16* __restrict__ A, int lda, long sA,
    const u16* __restrict__ B, int ldb, long sB, int K,
    const float* __restrict__ bias,   // EPI0
    const float* __restrict__ pos,    // EPI1
    u16* __restrict__ Cb, int ldc, long sC,  // EPI0: qd | EPI1: S bf16 out
    u16* __restrict__ KD,             // EPI0: dense k out [row][c]
    u16* __restrict__ VT,             // EPI0: transposed v out [b][c][j]
    float* __restrict__ CT, long sCT, // EPI2: f32 out [col*NTOK + row]
    float* __restrict__ RS)           // EPI1: atomic row sums; EPI2: read
{
  // LDS: A kh0 @0, A kh1 @8K, B kh0 @16K, B kh1 @24K  (32KB total)
  __shared__ char smem[32768];

  // chunked bijective XCD swizzle: xcd k owns m-chunk, intra m-fastest.
  const int GX = gridDim.x, GY = gridDim.y;
  const int hb = ((int)blockIdx.z * GY + blockIdx.y) * GX + blockIdx.x;
  const int MX = GX >> 3;
  const int k8 = hb & 7, j8 = hb >> 3;
  const int m = k8 * MX + (j8 % MX);
  const int rest = j8 / MX;
  const int n = rest % GY;
  const int bz = rest / GY;

  A += (size_t)bz * sA;
  B += (size_t)bz * sB;
  const int bm0 = m * 128;
  const int bn0 = n * 128;

  const int t = threadIdx.x;
  const int wave = t >> 6;
  const int wm = wave >> 1, wn = wave & 1;
  const int MROW = wm * 64, NCOL = wn * 64;
  const int lr = t & 15, lk = (t & 63) >> 4;
  // per-lane fragment byte offset within a k-half region (bank-perfect)
  const int fragoff = lr * 64 + (((lk + (lr >> 1)) & 3) << 4);

  const long lda2 = (long)lda * 2, ldb2 = (long)ldb * 2;
  const char* Agb = (const char*)A + (size_t)bm0 * lda2;
  const char* Bgb = (const char*)B + (size_t)bn0 * ldb2;

  f32x4 acc[4][4];
#pragma unroll
  for (int mm = 0; mm < 4; ++mm)
#pragma unroll
    for (int nn = 0; nn < 4; ++nn) acc[mm][nn] = (f32x4){0.f, 0.f, 0.f, 0.f};

  const int nt = K >> 6;
  for (int kt = 0; kt < nt; ++kt) {
    __syncthreads();   // all prior LDS reads complete everywhere
    const long kb = (long)kt * 128;
    stage128(Agb + kb,      lda2, smem,          t);
    stage128(Agb + kb + 64, lda2, smem + 8192,   t);
    stage128(Bgb + kb,      ldb2, smem + 16384,  t);
    stage128(Bgb + kb + 64, ldb2, smem + 24576,  t);
    __syncthreads();   // implies vmcnt(0): staged data landed

#pragma unroll
    for (int ks = 0; ks < 2; ++ks) {
      const char* Ab = smem + ks * 8192;
      const char* Bb = smem + 16384 + ks * 8192;
      bf16x8 av[4], bv[4];
#pragma unroll
      for (int i = 0; i < 4; ++i)
        av[i] = *(const bf16x8*)(Ab + (MROW + i * 16) * 64 + fragoff);
#pragma unroll
      for (int i = 0; i < 4; ++i)
        bv[i] = *(const bf16x8*)(Bb + (NCOL + i * 16) * 64 + fragoff);
#pragma unroll
      for (int mm = 0; mm < 4; ++mm)
#pragma unroll
        for (int nn = 0; nn < 4; ++nn)
          acc[mm][nn] = __builtin_amdgcn_mfma_f32_16x16x32_bf16(av[mm], bv[nn],
                                                                acc[mm][nn], 0, 0, 0);
    }
  }

  // epilogue: lane holds col fixed, rows lk*4 + r consecutive
#pragma unroll
  for (int mm = 0; mm < 4; ++mm) {
    const int row = bm0 + MROW + mm * 16 + (lk << 2);
    float rs[4] = {0.f, 0.f, 0.f, 0.f};   // EPI1 row-sum partials
    float inv[4];
    if (EPI == 2) {
      const float4 rsv = *(const float4*)(RS + (size_t)bz * NTOK + row);
      inv[0] = 1.f / rsv.x; inv[1] = 1.f / rsv.y;
      inv[2] = 1.f / rsv.z; inv[3] = 1.f / rsv.w;
    }
#pragma unroll
    for (int nn = 0; nn < 4; ++nn) {
      const int col = bn0 + NCOL + nn * 16 + lr;
      f32x4 v = acc[mm][nn];
      if (EPI == 0) {
        const float bb = bias[col];
        if (col < CDIM) {
          // dense q
#pragma unroll
          for (int r = 0; r < 4; ++r)
            Cb[(size_t)(row + r) * CDIM + col] = f2bf(v[r] + bb);
        } else if (col < 2 * CDIM) {
          // dense k
          const int c1 = col - CDIM;
#pragma unroll
          for (int r = 0; r < 4; ++r)
            KD[(size_t)(row + r) * CDIM + c1] = f2bf(v[r] + bb);
        } else {
          const int bq = row >> 11;
          const int j = row & (NTOK - 1);
          const int c2 = col - 2 * CDIM;
          uint2 pk;
          pk.x = (u32)f2bf(v[0] + bb) | ((u32)f2bf(v[1] + bb) << 16);
          pk.y = (u32)f2bf(v[2] + bb) | ((u32)f2bf(v[3] + bb) << 16);
          *(uint2*)&VT[((size_t)bq * CDIM + c2) * NTOK + j] = pk;
        }
      } else if (EPI == 1) {
        // P~ = exp(s*scale + pos), unnormalized (scores bounded, no max needed)
        u16* Cp = Cb + (size_t)bz * sC;
#pragma unroll
        for (int r = 0; r < 4; ++r) {
          float sv = v[r] * SM_SCALE + pos[(size_t)(row + r) * NTOK + col];
          float e = __expf(sv);
          rs[r] += e;
          Cp[(size_t)(row + r) * ldc + col] = f2bf(e);
        }
      } else {
        float* o = CT + (size_t)bz * sCT + (size_t)col * NTOK + row;
        f32x4 w;
        w[0] = v[0] * inv[0]; w[1] = v[1] * inv[1];
        w[2] = v[2] * inv[2]; w[3] = v[3] * inv[3];
        *(f32x4*)o = w;
      }
    }
    if (EPI == 1) {
      // reduce rs over the 16 lr-lanes, then one atomic per row
#pragma unroll
      for (int r = 0; r < 4; ++r) {
#pragma unroll
        for (int mk = 1; mk <= 8; mk <<= 1)
          rs[r] += __shfl_xor(rs[r], mk, 64);
      }
      if (lr == 0) {
        float* rp = RS + (size_t)bz * NTOK + row;
        atomicAdd(rp + 0, rs[0]);
        atomicAdd(rp + 1, rs[1]);
        atomicAdd(rp + 2, rs[2]);
        atomicAdd(rp + 3, rs[3]);
      }
    }
  }
}

extern "C" void kernel_launch(void* const* d_in, const int* in_sizes, int n_in,
                              void* d_out, int out_size, void* d_ws, size_t ws_size,
                              hipStream_t stream) {
  const float* x     = (const float*)d_in[0];
  const float* pos   = (const float*)d_in[1];
  const float* gamma = (const float*)d_in[2];
  const float* beta  = (const float*)d_in[3];
  const float* W     = (const float*)d_in[4];
  const float* bias  = (const float*)d_in[5];
  float* out = (float*)d_out;
  char* ws = (char*)d_ws;

  // workspace layout (102 MB + 32 KB)
  u16* Wb  = (u16*)(ws);                    //  6 MB  [3072,1024] bf16
  u16* h   = (u16*)(ws + (6ll << 20));      // 16 MB  [8192,1024] bf16
  u16* qd  = (u16*)(ws + (22ll << 20));     // 16 MB  [8192,1024] bf16 dense q
  u16* kd  = (u16*)(ws + (38ll << 20));     // 16 MB  [8192,1024] bf16 dense k
  u16* vT  = (u16*)(ws + (54ll << 20));     // 16 MB  [4][1024][2048] bf16
  u16* S   = (u16*)(ws + (70ll << 20));     // 32 MB  [4][2048][2048] bf16 (P~)
  float* RS = (float*)(ws + (102ll << 20)); // 32 KB row sums

  wconv_kernel<<<dim3((QKVD * CDIM / 8 + 255) / 256), 256, 0, stream>>>(
      W, Wb, QKVD * CDIM / 8, RS);
  ln_kernel<<<dim3(BSZ * (NTOK / 32)), 512, 0, stream>>>(x, gamma, beta, h);

  // qkv = h @ W^T + b  (M=8192, N=3072, K=1024); q,k dense; v transposed
  gemm_kernel<0><<<dim3(MTOT / 128, QKVD / 128, 1), 256, 0, stream>>>(
      h, CDIM, 0, Wb, CDIM, 0, CDIM,
      bias, nullptr, qd, CDIM, 0, kd, vT, nullptr, 0, nullptr);

  // P~ = exp(q @ k^T * scale + position), row sums -> RS (per batch M=N=2048, K=1024)
  gemm_kernel<1><<<dim3(NTOK / 128, NTOK / 128, BSZ), 256, 0, stream>>>(
      qd, CDIM, (long)NTOK * CDIM, kd, CDIM, (long)NTOK * CDIM, CDIM,
      nullptr, pos, S, NTOK, (long)NTOK * NTOK, nullptr, nullptr, nullptr, 0, RS);

  // out = (P~ @ vT^T) / rowsum, written transposed to [B, C, N] f32
  gemm_kernel<2><<<dim3(NTOK / 128, CDIM / 128, BSZ), 256, 0, stream>>>(
      S, NTOK, (long)NTOK * NTOK, vT, NTOK, (long)CDIM * NTOK, NTOK,
      nullptr, nullptr, nullptr, 0, 0, nullptr, nullptr, out, (long)CDIM * NTOK, RS);
}

// Round 13
// 171.224 us; speedup vs baseline: 1.0504x; 1.0045x over previous
//
#include <hip/hip_runtime.h>
#include <stdint.h>

typedef unsigned short u16;
typedef unsigned int u32;

#define NTOK 2048
#define CDIM 1024
#define BSZ  4
#define MTOT (BSZ * NTOK)
#define QKVD 3072
#define SM_SCALE 0.02209708691207961f   // 1/sqrt(2048)

typedef __bf16 bf16x8 __attribute__((ext_vector_type(8)));
typedef float f32x4 __attribute__((ext_vector_type(4)));

__device__ __forceinline__ u16 f2bf(float f) {
  u32 u = __float_as_uint(f);
  u += 0x7fffu + ((u >> 16) & 1u);   // round-to-nearest-even
  return (u16)(u >> 16);
}

// ---------------- W fp32 -> bf16 convert (+ RS zero fold-in) ----------------
__global__ __launch_bounds__(256) void wconv_kernel(const float* __restrict__ W,
                                                    u16* __restrict__ Wb, int n8,
                                                    float* __restrict__ RS) {
  int i = blockIdx.x * 256 + threadIdx.x;
  if (i < MTOT) RS[i] = 0.f;
  if (i >= n8) return;
  const float4* p = (const float4*)W + (size_t)i * 2;
  float4 a = p[0], b = p[1];
  uint4 o;
  o.x = (u32)f2bf(a.x) | ((u32)f2bf(a.y) << 16);
  o.y = (u32)f2bf(a.z) | ((u32)f2bf(a.w) << 16);
  o.z = (u32)f2bf(b.x) | ((u32)f2bf(b.y) << 16);
  o.w = (u32)f2bf(b.z) | ((u32)f2bf(b.w) << 16);
  ((uint4*)Wb)[i] = o;
}

// ---------------- one-pass transpose + LayerNorm: x[B,C,N] -> h[B*N, C] bf16 ----
__global__ __launch_bounds__(512) void ln_kernel(const float* __restrict__ x,
                                                 const float* __restrict__ gamma,
                                                 const float* __restrict__ beta,
                                                 u16* __restrict__ h) {
  int blk = blockIdx.x;          // BSZ * (NTOK/32) = 256
  int b = blk >> 6;
  int n0 = (blk & 63) << 5;
  int t = threadIdx.x;
  int nl = t & 31;               // token lane
  int cp = t >> 5;               // 0..15 c-partition
  const float* xb = x + (size_t)b * CDIM * NTOK + n0 + nl;

  float v[64];
  float s = 0.f, ss = 0.f;
#pragma unroll
  for (int k = 0; k < 64; ++k) {
    v[k] = xb[(size_t)(cp + (k << 4)) * NTOK];
    s += v[k]; ss += v[k] * v[k];
  }
  __shared__ float ps[16][32], pss[16][32];
  __shared__ float mean_s[32], rstd_s[32];
  ps[cp][nl] = s; pss[cp][nl] = ss;
  __syncthreads();
  if (t < 32) {
    float m = 0.f, q = 0.f;
#pragma unroll
    for (int p = 0; p < 16; ++p) { m += ps[p][t]; q += pss[p][t]; }
    float mu = m * (1.f / CDIM);
    float var = q * (1.f / CDIM) - mu * mu;
    mean_s[t] = mu;
    rstd_s[t] = rsqrtf(var + 1e-5f);
  }
  __syncthreads();
  float mu_n = mean_s[nl], rs_n = rstd_s[nl];

  __shared__ float tile[64][33];
  int tn = t >> 4, cl = t & 15;
#pragma unroll
  for (int kk = 0; kk < 16; ++kk) {
    __syncthreads();
#pragma unroll
    for (int i = 0; i < 4; ++i) {
      int c = (kk << 6) + (i << 4) + cp;     // = kk*64 + i*16 + cp
      tile[(i << 4) + cp][nl] = (v[(kk << 2) + i] - mu_n) * rs_n * gamma[c] + beta[c];
    }
    __syncthreads();
    uint2 pk;
    pk.x = (u32)f2bf(tile[(cl << 2) + 0][tn]) | ((u32)f2bf(tile[(cl << 2) + 1][tn]) << 16);
    pk.y = (u32)f2bf(tile[(cl << 2) + 2][tn]) | ((u32)f2bf(tile[(cl << 2) + 3][tn]) << 16);
    *(uint2*)&h[(size_t)(b * NTOK + n0 + tn) * CDIM + (kk << 6) + (cl << 2)] = pk;
  }
}

// ---------------- m97-style bf16 GEMM, B^T layout, 128x128 tile ----------------
// C[row,col] = sum_k A[row,k]*B[col,k]. BK=64, 4 waves (2Mx2N), 32KB LDS,
// single-buffered stage->sync->compute; cross-block overlap does the pipelining.
// bf16 outputs are LDS-repacked per 32x128 slab -> coalesced uint4 row stores.
__device__ __forceinline__ void gld_lds16(const void* g, void* l) {
  __builtin_amdgcn_global_load_lds(
      (const __attribute__((address_space(1))) void*)g,
      (__attribute__((address_space(3))) void*)l, 16, 0, 0);
}

// stage a [128 rows][64B] k-half region with 256 threads (2 gld/thread).
// LDS dest linear (wave-uniform + lane*16); global source slot-permuted so
// LDS (row, s) holds global slot (s - (row>>1))&3  -> conflict-free reads.
__device__ __forceinline__ void stage128(const char* g, long ld, char* lds, int t) {
  const long rb = (long)(t >> 2) * ld + ((((t & 3) - (t >> 3)) & 3) << 4);
#pragma unroll
  for (int i = 0; i < 2; ++i)
    gld_lds16(g + rb + (long)(i * 64) * ld,
              lds + ((t >> 6) << 10) + (i << 12));
}

template <int EPI>
__global__ __launch_bounds__(256, (EPI == 1) ? 4 : 3) void gemm_kernel(
    const u16* __restrict__ A, int lda, long sA,
    const u16* __restrict__ B, int ldb, long sB, int K,
    const float* __restrict__ bias,   // EPI0
    const float* __restrict__ pos,    // EPI1
    u16* __restrict__ Cb, int ldc, long sC,  // EPI0: qd | EPI1: S bf16 out
    u16* __restrict__ KD,             // EPI0: dense k out [row][c]
    u16* __restrict__ VT,             // EPI0: transposed v out [b][c][j]
    float* __restrict__ CT, long sCT, // EPI2: f32 out [col*NTOK + row]
    float* __restrict__ RS)           // EPI1: atomic row sums; EPI2: read
{
  // LDS: A kh0 @0, A kh1 @8K, B kh0 @16K, B kh1 @24K  (32KB total)
  __shared__ char smem[32768];

  // chunked bijective XCD swizzle: xcd k owns m-chunk, intra m-fastest.
  const int GX = gridDim.x, GY = gridDim.y;
  const int hb = ((int)blockIdx.z * GY + blockIdx.y) * GX + blockIdx.x;
  const int MX = GX >> 3;
  const int k8 = hb & 7, j8 = hb >> 3;
  const int m = k8 * MX + (j8 % MX);
  const int rest = j8 / MX;
  const int n = rest % GY;
  const int bz = rest / GY;

  A += (size_t)bz * sA;
  B += (size_t)bz * sB;
  const int bm0 = m * 128;
  const int bn0 = n * 128;

  const int t = threadIdx.x;
  const int wave = t >> 6;
  const int wm = wave >> 1, wn = wave & 1;
  const int MROW = wm * 64, NCOL = wn * 64;
  const int lr = t & 15, lk = (t & 63) >> 4;
  // per-lane fragment byte offset within a k-half region (bank-perfect)
  const int fragoff = lr * 64 + (((lk + (lr >> 1)) & 3) << 4);

  const long lda2 = (long)lda * 2, ldb2 = (long)ldb * 2;
  const char* Agb = (const char*)A + (size_t)bm0 * lda2;
  const char* Bgb = (const char*)B + (size_t)bn0 * ldb2;

  f32x4 acc[4][4];
#pragma unroll
  for (int mm = 0; mm < 4; ++mm)
#pragma unroll
    for (int nn = 0; nn < 4; ++nn) acc[mm][nn] = (f32x4){0.f, 0.f, 0.f, 0.f};

  const int nt = K >> 6;
  for (int kt = 0; kt < nt; ++kt) {
    __syncthreads();   // all prior LDS reads complete everywhere
    const long kb = (long)kt * 128;
    stage128(Agb + kb,      lda2, smem,          t);
    stage128(Agb + kb + 64, lda2, smem + 8192,   t);
    stage128(Bgb + kb,      ldb2, smem + 16384,  t);
    stage128(Bgb + kb + 64, ldb2, smem + 24576,  t);
    __syncthreads();   // implies vmcnt(0): staged data landed

#pragma unroll
    for (int ks = 0; ks < 2; ++ks) {
      const char* Ab = smem + ks * 8192;
      const char* Bb = smem + 16384 + ks * 8192;
      bf16x8 av[4], bv[4];
#pragma unroll
      for (int i = 0; i < 4; ++i)
        av[i] = *(const bf16x8*)(Ab + (MROW + i * 16) * 64 + fragoff);
#pragma unroll
      for (int i = 0; i < 4; ++i)
        bv[i] = *(const bf16x8*)(Bb + (NCOL + i * 16) * 64 + fragoff);
#pragma unroll
      for (int mm = 0; mm < 4; ++mm)
#pragma unroll
        for (int nn = 0; nn < 4; ++nn)
          acc[mm][nn] = __builtin_amdgcn_mfma_f32_16x16x32_bf16(av[mm], bv[nn],
                                                                acc[mm][nn], 0, 0, 0);
    }
  }

  // ---------------- epilogue ----------------
  if (EPI == 2) {
#pragma unroll
    for (int mm = 0; mm < 4; ++mm) {
      const int row = bm0 + MROW + mm * 16 + (lk << 2);
      const float4 rsv = *(const float4*)(RS + (size_t)bz * NTOK + row);
      float inv[4] = {1.f / rsv.x, 1.f / rsv.y, 1.f / rsv.z, 1.f / rsv.w};
#pragma unroll
      for (int nn = 0; nn < 4; ++nn) {
        const int col = bn0 + NCOL + nn * 16 + lr;
        f32x4 v = acc[mm][nn];
        float* o = CT + (size_t)bz * sCT + (size_t)col * NTOK + row;
        f32x4 w;
        w[0] = v[0] * inv[0]; w[1] = v[1] * inv[1];
        w[2] = v[2] * inv[2]; w[3] = v[3] * inv[3];
        *(f32x4*)o = w;
      }
    }
    return;
  }

  if (EPI == 0 && bn0 >= 2 * CDIM) {
    // v-path: transposed uint2-packed writes (already coalesced-ish)
#pragma unroll
    for (int mm = 0; mm < 4; ++mm) {
      const int row = bm0 + MROW + mm * 16 + (lk << 2);
#pragma unroll
      for (int nn = 0; nn < 4; ++nn) {
        const int col = bn0 + NCOL + nn * 16 + lr;
        const float bb = bias[col];
        f32x4 v = acc[mm][nn];
        const int bq = row >> 11;
        const int j = row & (NTOK - 1);
        const int c2 = col - 2 * CDIM;
        uint2 pk;
        pk.x = (u32)f2bf(v[0] + bb) | ((u32)f2bf(v[1] + bb) << 16);
        pk.y = (u32)f2bf(v[2] + bb) | ((u32)f2bf(v[3] + bb) << 16);
        *(uint2*)&VT[((size_t)bq * CDIM + c2) * NTOK + j] = pk;
      }
    }
    return;
  }

  // LDS-repacked bf16 store path (EPI0 q/k, EPI1 S).
  // Slab mm: 32 rows x 128 cols bf16 (8KB) in smem; write swizzled
  // (col ^ (lk<<3) u16), read back row-major, store coalesced uint4 rows.
  u16* tb = (u16*)smem;
  u16* dst;
  int ldd, colbase;
  if (EPI == 0) {
    if (bn0 < CDIM) { dst = Cb; colbase = bn0; }
    else            { dst = KD; colbase = bn0 - CDIM; }
    ldd = CDIM;
  } else {
    dst = Cb + (size_t)bz * sC; colbase = bn0; ldd = ldc;
  }
  float bb[4];
#pragma unroll
  for (int nn = 0; nn < 4; ++nn)
    bb[nn] = (EPI == 0) ? bias[bn0 + NCOL + nn * 16 + lr] : 0.f;

#pragma unroll
  for (int mm = 0; mm < 4; ++mm) {
    const int row = bm0 + MROW + mm * 16 + (lk << 2);
    float rs[4] = {0.f, 0.f, 0.f, 0.f};
    __syncthreads();   // LDS free (frag reads done / prev slab stored)
#pragma unroll
    for (int nn = 0; nn < 4; ++nn) {
      const int coll = NCOL + nn * 16 + lr;            // block-local col
      f32x4 v = acc[mm][nn];
#pragma unroll
      for (int r = 0; r < 4; ++r) {
        u16 ov;
        if (EPI == 0) {
          ov = f2bf(v[r] + bb[nn]);
        } else {
          float sv = v[r] * SM_SCALE + pos[(size_t)(row + r) * NTOK + colbase + coll];
          float e = __expf(sv);
          rs[r] += e;
          ov = f2bf(e);
        }
        tb[(wm * 16 + lk * 4 + r) * 128 + (coll ^ (lk << 3))] = ov;
      }
    }
    if (EPI == 1) {
#pragma unroll
      for (int r = 0; r < 4; ++r) {
#pragma unroll
        for (int mk = 1; mk <= 8; mk <<= 1)
          rs[r] += __shfl_xor(rs[r], mk, 64);
      }
      if (lr == 0) {
        float* rp = RS + (size_t)bz * NTOK + row;
        atomicAdd(rp + 0, rs[0]);
        atomicAdd(rp + 1, rs[1]);
        atomicAdd(rp + 2, rs[2]);
        atomicAdd(rp + 3, rs[3]);
      }
    }
    __syncthreads();   // slab complete
#pragma unroll
    for (int i = 0; i < 2; ++i) {
      const int u = i * 256 + t;
      const int rsl = u >> 4;            // 0..31 slab row
      const int cc  = u & 15;            // 16B chunk within row
      const int band = rsl >> 4, r16 = rsl & 15;
      const int grow = bm0 + band * 64 + mm * 16 + r16;
      const int ccs = cc ^ ((r16 >> 2) & 3);   // unswizzle source chunk
      *(uint4*)&dst[(size_t)grow * ldd + colbase + cc * 8] =
          *(const uint4*)&tb[rsl * 128 + ccs * 8];
    }
  }
}

extern "C" void kernel_launch(void* const* d_in, const int* in_sizes, int n_in,
                              void* d_out, int out_size, void* d_ws, size_t ws_size,
                              hipStream_t stream) {
  const float* x     = (const float*)d_in[0];
  const float* pos   = (const float*)d_in[1];
  const float* gamma = (const float*)d_in[2];
  const float* beta  = (const float*)d_in[3];
  const float* W     = (const float*)d_in[4];
  const float* bias  = (const float*)d_in[5];
  float* out = (float*)d_out;
  char* ws = (char*)d_ws;

  // workspace layout (102 MB + 32 KB)
  u16* Wb  = (u16*)(ws);                    //  6 MB  [3072,1024] bf16
  u16* h   = (u16*)(ws + (6ll << 20));      // 16 MB  [8192,1024] bf16
  u16* qd  = (u16*)(ws + (22ll << 20));     // 16 MB  [8192,1024] bf16 dense q
  u16* kd  = (u16*)(ws + (38ll << 20));     // 16 MB  [8192,1024] bf16 dense k
  u16* vT  = (u16*)(ws + (54ll << 20));     // 16 MB  [4][1024][2048] bf16
  u16* S   = (u16*)(ws + (70ll << 20));     // 32 MB  [4][2048][2048] bf16 (P~)
  float* RS = (float*)(ws + (102ll << 20)); // 32 KB row sums

  wconv_kernel<<<dim3((QKVD * CDIM / 8 + 255) / 256), 256, 0, stream>>>(
      W, Wb, QKVD * CDIM / 8, RS);
  ln_kernel<<<dim3(BSZ * (NTOK / 32)), 512, 0, stream>>>(x, gamma, beta, h);

  // qkv = h @ W^T + b  (M=8192, N=3072, K=1024); q,k dense; v transposed
  gemm_kernel<0><<<dim3(MTOT / 128, QKVD / 128, 1), 256, 0, stream>>>(
      h, CDIM, 0, Wb, CDIM, 0, CDIM,
      bias, nullptr, qd, CDIM, 0, kd, vT, nullptr, 0, nullptr);

  // P~ = exp(q @ k^T * scale + position), row sums -> RS (per batch M=N=2048, K=1024)
  gemm_kernel<1><<<dim3(NTOK / 128, NTOK / 128, BSZ), 256, 0, stream>>>(
      qd, CDIM, (long)NTOK * CDIM, kd, CDIM, (long)NTOK * CDIM, CDIM,
      nullptr, pos, S, NTOK, (long)NTOK * NTOK, nullptr, nullptr, nullptr, 0, RS);

  // out = (P~ @ vT^T) / rowsum, written transposed to [B, C, N] f32
  gemm_kernel<2><<<dim3(NTOK / 128, CDIM / 128, BSZ), 256, 0, stream>>>(
      S, NTOK, (long)NTOK * NTOK, vT, NTOK, (long)CDIM * NTOK, NTOK,
      nullptr, nullptr, nullptr, 0, 0, nullptr, nullptr, out, (long)CDIM * NTOK, RS);
}